// Round 10
// baseline (11115.910 us; speedup 1.0000x reference)
//
#include <hip/hip_runtime.h>
#include <math.h>

// Problem constants
#define NB 1024      // batch
#define NH 512       // hidden
#define NT 256       // time steps
#define NCD 2        // per-step output dims

typedef unsigned short u16;
typedef __bf16 bf16x8 __attribute__((ext_vector_type(8)));
typedef float  f32x4  __attribute__((ext_vector_type(4)));

#define MFMA_BF16 __builtin_amdgcn_mfma_f32_16x16x32_bf16

__device__ __forceinline__ float sigf(float x) { return 1.0f / (1.0f + expf(-x)); }
__device__ __forceinline__ float b2f(u16 u) {
    union { unsigned i; float f; } v; v.i = ((unsigned)u) << 16; return v.f;
}
__device__ __forceinline__ u16 f2b(float f) {   // RTNE
    union { float f; unsigned i; } v; v.f = f;
    unsigned r = v.i + 0x7fffu + ((v.i >> 16) & 1u);
    return (u16)(r >> 16);
}

// async 16B global -> LDS (direct-to-shared DMA); lane L lands at base+L*16.
__device__ __forceinline__ void async_cp16(const void* gptr, void* lptr) {
    __builtin_amdgcn_global_load_lds(
        (const __attribute__((address_space(1))) unsigned int*)gptr,
        (__attribute__((address_space(3))) unsigned int*)lptr,
        16, 0, 0);
}

// ---------------------------------------------------------------------------
// weight conversion fp32 -> bf16 (three 2048x512 LSTM weights)
// ---------------------------------------------------------------------------
__global__ __launch_bounds__(256) void convert3(
    const float* __restrict__ a, const float* __restrict__ b,
    const float* __restrict__ c,
    u16* __restrict__ oa, u16* __restrict__ ob, u16* __restrict__ oc)
{
    const int i = blockIdx.x * 256 + threadIdx.x;   // < 2048*512
    oa[i] = f2b(a[i]); ob[i] = f2b(b[i]); oc[i] = f2b(c[i]);
}

__global__ __launch_bounds__(256) void bsum_k(
    const float* __restrict__ bi1, const float* __restrict__ bh1,
    const float* __restrict__ bi2, const float* __restrict__ bh2,
    float* __restrict__ o1, float* __restrict__ o2)
{
    const int i = blockIdx.x * 256 + threadIdx.x;   // < 2048
    o1[i] = bi1[i] + bh1[i];
    o2[i] = bi2[i] + bh2[i];
}

// One-time transpose Wo1 (256x512) fp32 -> Wo1T (512x256) bf16 [R7-verified]
__global__ __launch_bounds__(256) void transpose_wo1(
    const float* __restrict__ Wo1, u16* __restrict__ Wo1T)
{
    const int idx = blockIdx.x * 256 + threadIdx.x;  // < 256*512
    const int r = idx >> 9, k = idx & 511;
    Wo1T[k * 256 + r] = f2b(Wo1[idx]);
}

// ---------------------------------------------------------------------------
// init: [h0 | c0] = z @ W_proj^T + b_proj ; h0 (bf16) -> h1,h2 ; c0 (f32)
// ---------------------------------------------------------------------------
__global__ __launch_bounds__(256) void init_kernel(
    const float* __restrict__ zp, const float* __restrict__ zs,
    const float* __restrict__ zst, const float* __restrict__ Wp,
    const float* __restrict__ bp,
    u16* __restrict__ h1, float* __restrict__ c1,
    u16* __restrict__ h2, float* __restrict__ c2)
{
    __shared__ float z[4][256];
    const int tid = threadIdx.x;
    const int b0  = blockIdx.x * 4;
    for (int i = tid; i < 4 * 256; i += 256) {
        const int bb = i >> 8, k = i & 255;
        float v;
        if (k < 64)       v = zp [(b0 + bb) * 64  + k];
        else if (k < 128) v = zs [(b0 + bb) * 64  + (k - 64)];
        else              v = zst[(b0 + bb) * 128 + (k - 128)];
        z[bb][k] = v;
    }
    __syncthreads();
    for (int rt = 0; rt < 4; ++rt) {
        const int r = rt * 256 + tid;          // 0..1023
        const float bias = bp[r];
        float a0 = bias, a1 = bias, a2 = bias, a3 = bias;
        for (int k = 0; k < 256; ++k) {
            const float w = Wp[r * 256 + k];
            a0 += z[0][k] * w; a1 += z[1][k] * w;
            a2 += z[2][k] * w; a3 += z[3][k] * w;
        }
        const float acc[4] = {a0, a1, a2, a3};
        for (int bb = 0; bb < 4; ++bb) {
            const int b = b0 + bb;
            if (r < NH) {
                h1[b * NH + r] = f2b(acc[bb]);
                h2[b * NH + r] = f2b(acc[bb]);
            } else {
                c1[b * NH + r - NH] = acc[bb];
                c2[b * NH + r - NH] = acc[bb];
            }
        }
    }
}

// ---------------------------------------------------------------------------
// FUSED: out(t-1) + lstm1(t).  512 blocks x 512 thr, 2 blocks/CU (all 512
// co-resident -> one-way flag wait cannot deadlock).
// phaseA (h2prev != null): out-MLP for this block's 2 batch rows (R8-verified
//   math, bit-identical reduction order); writes xb + d_out, publishes a
//   per-block flag (release fence + agent atomic store).  Overlaps with the
//   K-loop's first two staging DMAs (disjoint LDS; raw lgkm-only barriers
//   keep the DMAs in flight).
// phaseB: lstm1 K-loop (R9-verified triple-buffer depth-2 vmcnt pipeline).
// epilogue: waits same-grp 16 xb flags (s_sleep backoff; producers published
//   ~10 us earlier), reads xb via agent-scope atomic loads (coherence-point
//   reads -> no L2-invalidating acquire fence), then fused cell update.
// ---------------------------------------------------------------------------
__global__ __launch_bounds__(512, 4) void fused_out_lstm1(
    const u16* __restrict__ h2prev,     // null at t=0 -> skip phaseA
    const u16* __restrict__ A0,         // h1c
    const u16* __restrict__ W0,         // Whh1 bf16
    const float* __restrict__ bsum,     // bs1
    float* __restrict__ xb,             // x feedback (write phaseA, read epi)
    const float* __restrict__ Wx,       // Wih1 fp32
    const u16* __restrict__ W1t, const float* __restrict__ bo1,
    const float* __restrict__ Wo2, const float* __restrict__ bo2,
    float* __restrict__ outp,
    float* __restrict__ c, u16* __restrict__ hnext,
    unsigned* __restrict__ flags,
    const int t, const int do_lstm)
{
    __shared__ __align__(16) char smem[61440];   // 3 x (As 4KB | Ws 16KB)
    float* eg = (float*)smem;                    // epilogue alias [4][32][33]

    const int tid  = threadIdx.x;
    const int lane = tid & 63;
    const int wv   = tid >> 6;          // 0..7
    const int g    = wv & 3;            // gate
    const int mh   = wv >> 2;           // batch half (16 rows)
    const int l15  = lane & 15;
    const int q    = lane >> 4;         // 0..3
    const int bx   = blockIdx.x;
    const int ut   = (bx & 7) * 2 + ((bx >> 3) & 1);  // 0..15
    const int grp  = bx >> 4;                          // 0..31
    const int b0   = grp * 32;
    const int u0   = ut * 32;
    const int r0   = grp * 32 + ut * 2; // out-phase rows (2)

    // staging descriptors (same as R9). W: 2 chunks/wave; A: waves 0..3.
    int goffW0, goffW1, goffA = 0;
    {
        const int c0 = (wv * 2) * 64 + lane;        // 0..1023
        const int w0r = c0 >> 3;                    // g*32+uu
        goffW0 = ((w0r >> 5) * NH + u0 + (w0r & 31)) * NH + (((c0 & 7) ^ (w0r & 7)) * 8);
        const int c1i = (wv * 2 + 1) * 64 + lane;
        const int w1r = c1i >> 3;
        goffW1 = ((w1r >> 5) * NH + u0 + (w1r & 31)) * NH + (((c1i & 7) ^ (w1r & 7)) * 8);
        if (wv < 4) {
            const int ca = wv * 64 + lane;          // 0..255
            const int ar = ca >> 3;                 // batch row 0..31
            goffA = (b0 + ar) * NH + (((ca & 7) ^ (ar & 7)) * 8);
        }
    }

    auto issue = [&](int m, int bi) {
        const int k0 = (m & 7) * 64;
        char* base = smem + bi * 20480;        // As 4KB | Ws 16KB
        async_cp16((const void*)(W0 + goffW0 + k0),
                   (void*)(base + 4096 + (wv * 2) * 1024));
        async_cp16((const void*)(W0 + goffW1 + k0),
                   (void*)(base + 4096 + (wv * 2 + 1) * 1024));
        if (wv < 4)
            async_cp16((const void*)(A0 + goffA + k0),
                       (void*)(base + wv * 1024));
    };

    if (do_lstm) { issue(0, 0); issue(1, 1); }   // DMAs fly during phaseA

    // ---------------- phase A: out for step t-1 ----------------
    if (h2prev) {
        float* hsh = (float*)(smem + 40960);          // 4KB (buf2: safe until issue(2))
        float* red = (float*)(smem + 40960 + 4096);   // 16 floats
        for (int i = tid; i < 2 * NH; i += 512)
            hsh[i] = b2f(h2prev[(size_t)(r0 + (i >> 9)) * NH + (i & 511)]);
        asm volatile("s_waitcnt lgkmcnt(0)" ::: "memory");
        __builtin_amdgcn_s_barrier();                 // lgkm-only: DMAs stay in flight
        const int n  = tid & 255;
        const int hh = tid >> 8;                      // row 0/1
        const float* hr = hsh + hh * NH;
        float a = 0.f;
#pragma unroll 16
        for (int k = 0; k < NH; ++k)
            a += hr[k] * b2f(W1t[k * 256 + n]);       // coalesced, L2-hot
        const float s = fmaxf(a + bo1[n], 0.f);
        float p0 = s * Wo2[n], p1 = s * Wo2[256 + n];
#pragma unroll
        for (int off = 32; off > 0; off >>= 1) {
            p0 += __shfl_down(p0, off, 64);
            p1 += __shfl_down(p1, off, 64);
        }
        if (lane == 0) { red[wv * 2] = p0; red[wv * 2 + 1] = p1; }
        asm volatile("s_waitcnt lgkmcnt(0)" ::: "memory");
        __builtin_amdgcn_s_barrier();
        if (tid < 4) {
            const int hh2 = tid >> 1, cc = tid & 1;
            const int wb = hh2 * 4;                   // waves 0-3 row0, 4-7 row1
            const float y = red[wb * 2 + cc] + red[(wb + 1) * 2 + cc]
                          + red[(wb + 2) * 2 + cc] + red[(wb + 3) * 2 + cc]
                          + bo2[cc];
            const int b = r0 + hh2;
            xb[b * NCD + cc] = y;
            outp[(size_t)b * (NT * NCD) + (t - 1) * NCD + cc] = y;
        }
        if (wv == 0) {                                // xb writers are wave 0
            __builtin_amdgcn_fence(__ATOMIC_RELEASE, "agent");
            if (lane == 0 && do_lstm)
                __hip_atomic_store(&flags[(grp * 16 + ut) * 16], (unsigned)t,
                                   __ATOMIC_RELAXED, __HIP_MEMORY_SCOPE_AGENT);
        }
    }
    if (!do_lstm) return;                             // final out-only dispatch

    // ---------------- phase B: lstm1 K-loop (R9-verified) ----------------
    f32x4 acc[2];
    acc[0] = (f32x4){0.f, 0.f, 0.f, 0.f};
    acc[1] = (f32x4){0.f, 0.f, 0.f, 0.f};
    const int M = 8;
    int ci = 0;
    for (int m = 0; m < M; ++m) {
        if (m + 1 < M) {
            if (wv < 4) asm volatile("s_waitcnt vmcnt(3)" ::: "memory");
            else        asm volatile("s_waitcnt vmcnt(2)" ::: "memory");
        } else {
            asm volatile("s_waitcnt vmcnt(0)" ::: "memory");
        }
        __builtin_amdgcn_s_barrier();
        if (m + 2 < M) {
            int bi = ci + 2; if (bi >= 3) bi -= 3;
            issue(m + 2, bi);
        }
        const char* bA = smem + ci * 20480;
        const char* bW = bA + 4096;
#pragma unroll
        for (int khi = 0; khi < 2; ++khi) {
            bf16x8 bfr[2];
#pragma unroll
            for (int ni = 0; ni < 2; ++ni) {
                const int wrow = g * 32 + ni * 16 + l15;
                const int j = (khi * 4 + q) ^ (wrow & 7);
                bfr[ni] = *(const bf16x8*)(bW + wrow * 128 + j * 16);
            }
            const int row = mh * 16 + l15;
            const int j = (khi * 4 + q) ^ (row & 7);
            const bf16x8 av = *(const bf16x8*)(bA + row * 128 + j * 16);
            acc[0] = MFMA_BF16(av, bfr[0], acc[0], 0, 0, 0);
            acc[1] = MFMA_BF16(av, bfr[1], acc[1], 0, 0, 0);
        }
        ++ci; if (ci == 3) ci = 0;
    }

    __syncthreads();
    // eg[g][b_local][u_local], stride 33 ; C/D: row=q*4+r, col=l15 [m89]
#pragma unroll
    for (int ni = 0; ni < 2; ++ni)
#pragma unroll
        for (int r = 0; r < 4; ++r)
            eg[(g * 32 + mh * 16 + q * 4 + r) * 33 + ni * 16 + l15] = acc[ni][r];
    __syncthreads();

    // wait for same-grp xb producers (one-way; expected already done)
    if (t > 0) {
        if (tid < 16) {
            const unsigned tu = (unsigned)t;
            while (__hip_atomic_load(&flags[(grp * 16 + tid) * 16],
                                     __ATOMIC_RELAXED,
                                     __HIP_MEMORY_SCOPE_AGENT) < tu)
                __builtin_amdgcn_s_sleep(2);
        }
        __syncthreads();
    }

    // fused pointwise cell update: thread -> unit u, 2 batch rows
    const int u  = tid & 31;
    const int bq = tid >> 5;            // 0..15
    const int ug = u0 + u;
    float bs[4], wx0[4], wx1[4];
#pragma unroll
    for (int g4 = 0; g4 < 4; ++g4) bs[g4] = bsum[g4 * NH + ug];
#pragma unroll
    for (int g4 = 0; g4 < 4; ++g4) {
        wx0[g4] = Wx[(g4 * NH + ug) * 2 + 0];
        wx1[g4] = Wx[(g4 * NH + ug) * 2 + 1];
    }
#pragma unroll
    for (int jj = 0; jj < 2; ++jj) {
        const int bl = bq * 2 + jj;
        const int b  = b0 + bl;
        float gv[4];
#pragma unroll
        for (int g4 = 0; g4 < 4; ++g4) gv[g4] = eg[(g4 * 32 + bl) * 33 + u] + bs[g4];
        // coherence-point reads (agent atomics): no acquire fence needed
        const float x0 = __hip_atomic_load(&xb[b * 2 + 0], __ATOMIC_RELAXED,
                                           __HIP_MEMORY_SCOPE_AGENT);
        const float x1 = __hip_atomic_load(&xb[b * 2 + 1], __ATOMIC_RELAXED,
                                           __HIP_MEMORY_SCOPE_AGENT);
#pragma unroll
        for (int g4 = 0; g4 < 4; ++g4) gv[g4] += x0 * wx0[g4] + x1 * wx1[g4];
        const float iv = sigf(gv[0]);
        const float fv = sigf(gv[1]);
        const float gg = tanhf(gv[2]);
        const float ov = sigf(gv[3]);
        const size_t idx = (size_t)b * NH + ug;
        const float cn = fv * c[idx] + iv * gg;
        c[idx] = cn;
        hnext[idx] = f2b(ov * tanhf(cn));
    }
}

// ---------------------------------------------------------------------------
// LSTM2: R9-verified kernel, unchanged (npass=2, no x-term).
// ---------------------------------------------------------------------------
__global__ __launch_bounds__(512, 4) void lstm_mfma32(
    const u16* __restrict__ A0, const u16* __restrict__ W0,
    const u16* __restrict__ A1, const u16* __restrict__ W1,
    const float* __restrict__ bsum,
    const float* __restrict__ xin, const float* __restrict__ Wx,
    float* __restrict__ c, u16* __restrict__ hnext,
    const int npass)
{
    __shared__ __align__(16) char smem[61440];
    float* eg = (float*)smem;

    const int tid  = threadIdx.x;
    const int lane = tid & 63;
    const int wv   = tid >> 6;
    const int g    = wv & 3;
    const int mh   = wv >> 2;
    const int l15  = lane & 15;
    const int q    = lane >> 4;
    const int bx   = blockIdx.x;
    const int ut   = (bx & 7) * 2 + ((bx >> 3) & 1);
    const int grp  = bx >> 4;
    const int b0   = grp * 32;
    const int u0   = ut * 32;

    int goffW0, goffW1, goffA = 0;
    {
        const int c0 = (wv * 2) * 64 + lane;
        const int w0r = c0 >> 3;
        goffW0 = ((w0r >> 5) * NH + u0 + (w0r & 31)) * NH + (((c0 & 7) ^ (w0r & 7)) * 8);
        const int c1i = (wv * 2 + 1) * 64 + lane;
        const int w1r = c1i >> 3;
        goffW1 = ((w1r >> 5) * NH + u0 + (w1r & 31)) * NH + (((c1i & 7) ^ (w1r & 7)) * 8);
        if (wv < 4) {
            const int ca = wv * 64 + lane;
            const int ar = ca >> 3;
            goffA = (b0 + ar) * NH + (((ca & 7) ^ (ar & 7)) * 8);
        }
    }

    f32x4 acc[2];
    acc[0] = (f32x4){0.f, 0.f, 0.f, 0.f};
    acc[1] = (f32x4){0.f, 0.f, 0.f, 0.f};

    const int M = npass * 8;

    auto issue = [&](int m, int bi) {
        const u16* __restrict__ Ap = (m < 8) ? A0 : A1;
        const u16* __restrict__ Wp = (m < 8) ? W0 : W1;
        const int k0 = (m & 7) * 64;
        char* base = smem + bi * 20480;
        async_cp16((const void*)(Wp + goffW0 + k0),
                   (void*)(base + 4096 + (wv * 2) * 1024));
        async_cp16((const void*)(Wp + goffW1 + k0),
                   (void*)(base + 4096 + (wv * 2 + 1) * 1024));
        if (wv < 4)
            async_cp16((const void*)(Ap + goffA + k0),
                       (void*)(base + wv * 1024));
    };

    issue(0, 0);
    if (M > 1) issue(1, 1);
    int ci = 0;
    for (int m = 0; m < M; ++m) {
        if (m + 1 < M) {
            if (wv < 4) asm volatile("s_waitcnt vmcnt(3)" ::: "memory");
            else        asm volatile("s_waitcnt vmcnt(2)" ::: "memory");
        } else {
            asm volatile("s_waitcnt vmcnt(0)" ::: "memory");
        }
        __builtin_amdgcn_s_barrier();
        if (m + 2 < M) {
            int bi = ci + 2; if (bi >= 3) bi -= 3;
            issue(m + 2, bi);
        }
        const char* bA = smem + ci * 20480;
        const char* bW = bA + 4096;
#pragma unroll
        for (int khi = 0; khi < 2; ++khi) {
            bf16x8 bfr[2];
#pragma unroll
            for (int ni = 0; ni < 2; ++ni) {
                const int wrow = g * 32 + ni * 16 + l15;
                const int j = (khi * 4 + q) ^ (wrow & 7);
                bfr[ni] = *(const bf16x8*)(bW + wrow * 128 + j * 16);
            }
            const int row = mh * 16 + l15;
            const int j = (khi * 4 + q) ^ (row & 7);
            const bf16x8 av = *(const bf16x8*)(bA + row * 128 + j * 16);
            acc[0] = MFMA_BF16(av, bfr[0], acc[0], 0, 0, 0);
            acc[1] = MFMA_BF16(av, bfr[1], acc[1], 0, 0, 0);
        }
        ++ci; if (ci == 3) ci = 0;
    }

    __syncthreads();
#pragma unroll
    for (int ni = 0; ni < 2; ++ni)
#pragma unroll
        for (int r = 0; r < 4; ++r)
            eg[(g * 32 + mh * 16 + q * 4 + r) * 33 + ni * 16 + l15] = acc[ni][r];
    __syncthreads();

    const int u  = tid & 31;
    const int bq = tid >> 5;
    const int ug = u0 + u;
    float bs[4], wx0[4], wx1[4];
#pragma unroll
    for (int g4 = 0; g4 < 4; ++g4) bs[g4] = bsum[g4 * NH + ug];
    if (Wx) {
#pragma unroll
        for (int g4 = 0; g4 < 4; ++g4) {
            wx0[g4] = Wx[(g4 * NH + ug) * 2 + 0];
            wx1[g4] = Wx[(g4 * NH + ug) * 2 + 1];
        }
    }
#pragma unroll
    for (int jj = 0; jj < 2; ++jj) {
        const int bl = bq * 2 + jj;
        const int b  = b0 + bl;
        float gv[4];
#pragma unroll
        for (int g4 = 0; g4 < 4; ++g4) gv[g4] = eg[(g4 * 32 + bl) * 33 + u] + bs[g4];
        if (Wx) {
            const float x0 = xin[b * 2], x1 = xin[b * 2 + 1];
#pragma unroll
            for (int g4 = 0; g4 < 4; ++g4) gv[g4] += x0 * wx0[g4] + x1 * wx1[g4];
        }
        const float iv = sigf(gv[0]);
        const float fv = sigf(gv[1]);
        const float gg = tanhf(gv[2]);
        const float ov = sigf(gv[3]);
        const size_t idx = (size_t)b * NH + ug;
        const float cn = fv * c[idx] + iv * gg;
        c[idx] = cn;
        hnext[idx] = f2b(ov * tanhf(cn));
    }
}

// ---------------------------------------------------------------------------
extern "C" void kernel_launch(void* const* d_in, const int* in_sizes, int n_in,
                              void* d_out, int out_size, void* d_ws, size_t ws_size,
                              hipStream_t stream)
{
    const float* zp   = (const float*)d_in[0];
    const float* zsk  = (const float*)d_in[1];
    const float* zst  = (const float*)d_in[2];
    const float* Wp   = (const float*)d_in[3];
    const float* bp   = (const float*)d_in[4];
    const float* Wih1 = (const float*)d_in[5];
    const float* Whh1 = (const float*)d_in[6];
    const float* bih1 = (const float*)d_in[7];
    const float* bhh1 = (const float*)d_in[8];
    const float* Wih2 = (const float*)d_in[9];
    const float* Whh2 = (const float*)d_in[10];
    const float* bih2 = (const float*)d_in[11];
    const float* bhh2 = (const float*)d_in[12];
    const float* Wo1  = (const float*)d_in[13];
    const float* bo1  = (const float*)d_in[14];
    const float* Wo2  = (const float*)d_in[15];
    const float* bo2  = (const float*)d_in[16];

    const size_t BH = (size_t)NB * NH;          // 524288
    u16*   h1a   = (u16*)d_ws;
    u16*   h1b   = h1a + BH;
    u16*   h2a   = h1b + BH;
    u16*   h2b   = h2a + BH;
    float* c1    = (float*)(h2b + BH);
    float* c2    = c1 + BH;
    float* xb    = c2 + BH;                     // 2048 used (pad 4096)
    float* bs1   = xb + 4096;                   // 2048
    float* bs2   = bs1 + 2048;                  // 2048
    u16*   Wo1T  = (u16*)(bs2 + 2048);          // 131072 u16
    u16*   Whh1b = Wo1T + 131072;               // 1048576 each
    u16*   Wih2b = Whh1b + 1048576;
    u16*   Whh2b = Wih2b + 1048576;
    unsigned* flags = (unsigned*)(Whh2b + 1048576);  // 32 grps x 16 x 16 u32 = 32KB
    // total ~14.5 MB of d_ws

    convert3<<<(2048 * 512) / 256, 256, 0, stream>>>(Whh1, Wih2, Whh2, Whh1b, Wih2b, Whh2b);
    transpose_wo1<<<(256 * 512) / 256, 256, 0, stream>>>(Wo1, Wo1T);
    bsum_k<<<2048 / 256, 256, 0, stream>>>(bih1, bhh1, bih2, bhh2, bs1, bs2);
    hipMemsetAsync(xb, 0, NB * NCD * sizeof(float), stream);     // x0 = 0
    hipMemsetAsync(flags, 0, 32 * 16 * 16 * sizeof(unsigned), stream);
    init_kernel<<<NB / 4, 256, 0, stream>>>(zp, zsk, zst, Wp, bp, h1a, c1, h2a, c2);

    u16* h1c = h1a; u16* h1n = h1b;
    u16* h2c = h2a; u16* h2n = h2b;
    float* outp = (float*)d_out;
    for (int t = 0; t < NT; ++t) {
        fused_out_lstm1<<<512, 512, 0, stream>>>(
            (t == 0) ? (const u16*)0 : h2c, h1c, Whh1b, bs1, xb, Wih1,
            Wo1T, bo1, Wo2, bo2, outp, c1, h1n, flags, t, 1);
        lstm_mfma32<<<512, 512, 0, stream>>>(h1n, Wih2b, h2c, Whh2b,
                                             bs2, (const float*)0, (const float*)0,
                                             c2, h2n, 2);
        u16* tmp = h1c; h1c = h1n; h1n = tmp;
        tmp = h2c; h2c = h2n; h2n = tmp;
    }
    // final out for t = NT-1 (h2c now holds h2n(NT-1) after the last swap)
    fused_out_lstm1<<<512, 512, 0, stream>>>(
        h2c, h1c, Whh1b, bs1, xb, Wih1,
        Wo1T, bo1, Wo2, bo2, outp, c1, h1n, flags, NT, 0);
}

// Round 11
// 9402.859 us; speedup vs baseline: 1.1822x; 1.1822x over previous
//
#include <hip/hip_runtime.h>
#include <math.h>

// Problem constants
#define NB 1024      // batch
#define NH 512       // hidden
#define NT 256       // time steps
#define NCD 2        // per-step output dims

typedef unsigned short u16;
typedef unsigned long long u64;
typedef __bf16 bf16x8 __attribute__((ext_vector_type(8)));
typedef float  f32x4  __attribute__((ext_vector_type(4)));

#define MFMA_BF16 __builtin_amdgcn_mfma_f32_16x16x32_bf16

__device__ __forceinline__ float sigf(float x) { return 1.0f / (1.0f + expf(-x)); }
__device__ __forceinline__ float b2f(u16 u) {
    union { unsigned i; float f; } v; v.i = ((unsigned)u) << 16; return v.f;
}
__device__ __forceinline__ u16 f2b(float f) {   // RTNE
    union { float f; unsigned i; } v; v.f = f;
    unsigned r = v.i + 0x7fffu + ((v.i >> 16) & 1u);
    return (u16)(r >> 16);
}

// async 16B global -> LDS (direct-to-shared DMA); lane L lands at base+L*16.
__device__ __forceinline__ void async_cp16(const void* gptr, void* lptr) {
    __builtin_amdgcn_global_load_lds(
        (const __attribute__((address_space(1))) unsigned int*)gptr,
        (__attribute__((address_space(3))) unsigned int*)lptr,
        16, 0, 0);
}

// ---------------------------------------------------------------------------
// weight conversion fp32 -> bf16 (three 2048x512 LSTM weights)
// ---------------------------------------------------------------------------
__global__ __launch_bounds__(256) void convert3(
    const float* __restrict__ a, const float* __restrict__ b,
    const float* __restrict__ c,
    u16* __restrict__ oa, u16* __restrict__ ob, u16* __restrict__ oc)
{
    const int i = blockIdx.x * 256 + threadIdx.x;   // < 2048*512
    oa[i] = f2b(a[i]); ob[i] = f2b(b[i]); oc[i] = f2b(c[i]);
}

__global__ __launch_bounds__(256) void bsum_k(
    const float* __restrict__ bi1, const float* __restrict__ bh1,
    const float* __restrict__ bi2, const float* __restrict__ bh2,
    float* __restrict__ o1, float* __restrict__ o2)
{
    const int i = blockIdx.x * 256 + threadIdx.x;   // < 2048
    o1[i] = bi1[i] + bh1[i];
    o2[i] = bi2[i] + bh2[i];
}

// One-time transpose Wo1 (256x512) fp32 -> Wo1T (512x256) bf16 [R7-verified]
__global__ __launch_bounds__(256) void transpose_wo1(
    const float* __restrict__ Wo1, u16* __restrict__ Wo1T)
{
    const int idx = blockIdx.x * 256 + threadIdx.x;  // < 256*512
    const int r = idx >> 9, k = idx & 511;
    Wo1T[k * 256 + r] = f2b(Wo1[idx]);
}

// ---------------------------------------------------------------------------
// init: [h0 | c0] = z @ W_proj^T + b_proj ; h0 (bf16) -> h1,h2 ; c0 (f32)
// ---------------------------------------------------------------------------
__global__ __launch_bounds__(256) void init_kernel(
    const float* __restrict__ zp, const float* __restrict__ zs,
    const float* __restrict__ zst, const float* __restrict__ Wp,
    const float* __restrict__ bp,
    u16* __restrict__ h1, float* __restrict__ c1,
    u16* __restrict__ h2, float* __restrict__ c2)
{
    __shared__ float z[4][256];
    const int tid = threadIdx.x;
    const int b0  = blockIdx.x * 4;
    for (int i = tid; i < 4 * 256; i += 256) {
        const int bb = i >> 8, k = i & 255;
        float v;
        if (k < 64)       v = zp [(b0 + bb) * 64  + k];
        else if (k < 128) v = zs [(b0 + bb) * 64  + (k - 64)];
        else              v = zst[(b0 + bb) * 128 + (k - 128)];
        z[bb][k] = v;
    }
    __syncthreads();
    for (int rt = 0; rt < 4; ++rt) {
        const int r = rt * 256 + tid;          // 0..1023
        const float bias = bp[r];
        float a0 = bias, a1 = bias, a2 = bias, a3 = bias;
        for (int k = 0; k < 256; ++k) {
            const float w = Wp[r * 256 + k];
            a0 += z[0][k] * w; a1 += z[1][k] * w;
            a2 += z[2][k] * w; a3 += z[3][k] * w;
        }
        const float acc[4] = {a0, a1, a2, a3};
        for (int bb = 0; bb < 4; ++bb) {
            const int b = b0 + bb;
            if (r < NH) {
                h1[b * NH + r] = f2b(acc[bb]);
                h2[b * NH + r] = f2b(acc[bb]);
            } else {
                c1[b * NH + r - NH] = acc[bb];
                c2[b * NH + r - NH] = acc[bb];
            }
        }
    }
}

// ---------------------------------------------------------------------------
// FUSED: out(t-1) + lstm1(t).  512 blocks x 512 thr, 2 blocks/CU (all 512
// co-resident -> one-way wait cannot deadlock).
// Signaling is FENCE-FREE: producer packs (tag=t<<32 | float_bits(y)) into a
// u64 agent-scope RELAXED atomic store (4 per block).  Tag travels with the
// data word, so tag>=t implies value valid -- no release fence, no L2
// writeback (R10's regression: 512 release fences/step thrashed L2).
// Consumer: wave 0's 64 lanes poll the grp's 64 slots once (s_sleep backoff,
// producers published ~10us earlier), stage into LDS, all threads read LDS.
// phaseA = out-MLP, R8-verified math, bit-identical reduction order.
// phaseB = lstm1 K-loop, R9-verified triple-buffer depth-2 vmcnt pipeline.
// ---------------------------------------------------------------------------
__global__ __launch_bounds__(512, 4) void fused_out_lstm1(
    const u16* __restrict__ h2prev,     // null at t=0 -> skip phaseA
    const u16* __restrict__ A0,         // h1c
    const u16* __restrict__ W0,         // Whh1 bf16
    const float* __restrict__ bsum,     // bs1
    u64* __restrict__ xq,               // packed (tag,value) slots [NB*2]
    const float* __restrict__ Wx,       // Wih1 fp32
    const u16* __restrict__ W1t, const float* __restrict__ bo1,
    const float* __restrict__ Wo2, const float* __restrict__ bo2,
    float* __restrict__ outp,
    float* __restrict__ c, u16* __restrict__ hnext,
    const int t, const int do_lstm)
{
    __shared__ __align__(16) char smem[61440];   // 3 x (As 4KB | Ws 16KB)
    float* eg  = (float*)smem;                   // epilogue alias [4][32][33]
    float* xsh = (float*)(smem + 16896);         // 64 floats (after eg)

    const int tid  = threadIdx.x;
    const int lane = tid & 63;
    const int wv   = tid >> 6;          // 0..7
    const int g    = wv & 3;            // gate
    const int mh   = wv >> 2;           // batch half (16 rows)
    const int l15  = lane & 15;
    const int q    = lane >> 4;         // 0..3
    const int bx   = blockIdx.x;
    const int ut   = (bx & 7) * 2 + ((bx >> 3) & 1);  // 0..15
    const int grp  = bx >> 4;                          // 0..31
    const int b0   = grp * 32;
    const int u0   = ut * 32;
    const int r0   = grp * 32 + ut * 2; // out-phase rows (2)

    // staging descriptors (R9). W: 2 chunks/wave; A: waves 0..3.
    int goffW0, goffW1, goffA = 0;
    {
        const int c0 = (wv * 2) * 64 + lane;        // 0..1023
        const int w0r = c0 >> 3;                    // g*32+uu
        goffW0 = ((w0r >> 5) * NH + u0 + (w0r & 31)) * NH + (((c0 & 7) ^ (w0r & 7)) * 8);
        const int c1i = (wv * 2 + 1) * 64 + lane;
        const int w1r = c1i >> 3;
        goffW1 = ((w1r >> 5) * NH + u0 + (w1r & 31)) * NH + (((c1i & 7) ^ (w1r & 7)) * 8);
        if (wv < 4) {
            const int ca = wv * 64 + lane;          // 0..255
            const int ar = ca >> 3;                 // batch row 0..31
            goffA = (b0 + ar) * NH + (((ca & 7) ^ (ar & 7)) * 8);
        }
    }

    auto issue = [&](int m, int bi) {
        const int k0 = (m & 7) * 64;
        char* base = smem + bi * 20480;        // As 4KB | Ws 16KB
        async_cp16((const void*)(W0 + goffW0 + k0),
                   (void*)(base + 4096 + (wv * 2) * 1024));
        async_cp16((const void*)(W0 + goffW1 + k0),
                   (void*)(base + 4096 + (wv * 2 + 1) * 1024));
        if (wv < 4)
            async_cp16((const void*)(A0 + goffA + k0),
                       (void*)(base + wv * 1024));
    };

    if (do_lstm) { issue(0, 0); issue(1, 1); }   // DMAs fly during phaseA

    // ---------------- phase A: out for step t-1 ----------------
    if (h2prev) {
        float* hsh = (float*)(smem + 40960);          // 4KB (buf2: safe until issue(2))
        float* red = (float*)(smem + 40960 + 4096);   // 16 floats
        for (int i = tid; i < 2 * NH; i += 512)
            hsh[i] = b2f(h2prev[(size_t)(r0 + (i >> 9)) * NH + (i & 511)]);
        asm volatile("s_waitcnt lgkmcnt(0)" ::: "memory");
        __builtin_amdgcn_s_barrier();                 // lgkm-only: DMAs stay in flight
        const int n  = tid & 255;
        const int hh = tid >> 8;                      // row 0/1
        const float* hr = hsh + hh * NH;
        float a = 0.f;
#pragma unroll 16
        for (int k = 0; k < NH; ++k)
            a += hr[k] * b2f(W1t[k * 256 + n]);       // coalesced, L2-hot
        const float s = fmaxf(a + bo1[n], 0.f);
        float p0 = s * Wo2[n], p1 = s * Wo2[256 + n];
#pragma unroll
        for (int off = 32; off > 0; off >>= 1) {
            p0 += __shfl_down(p0, off, 64);
            p1 += __shfl_down(p1, off, 64);
        }
        if (lane == 0) { red[wv * 2] = p0; red[wv * 2 + 1] = p1; }
        asm volatile("s_waitcnt lgkmcnt(0)" ::: "memory");
        __builtin_amdgcn_s_barrier();
        if (tid < 4) {
            const int hh2 = tid >> 1, cc = tid & 1;
            const int wb = hh2 * 4;                   // waves 0-3 row0, 4-7 row1
            const float y = red[wb * 2 + cc] + red[(wb + 1) * 2 + cc]
                          + red[(wb + 2) * 2 + cc] + red[(wb + 3) * 2 + cc]
                          + bo2[cc];
            const int b = r0 + hh2;
            outp[(size_t)b * (NT * NCD) + (t - 1) * NCD + cc] = y;
            union { float f; unsigned u; } cv; cv.f = y;
            const u64 pk = ((u64)(unsigned)t << 32) | (u64)cv.u;
            __hip_atomic_store(&xq[b * NCD + cc], pk,
                               __ATOMIC_RELAXED, __HIP_MEMORY_SCOPE_AGENT);
        }
    }
    if (!do_lstm) return;                             // final out-only dispatch

    // ---------------- phase B: lstm1 K-loop (R9-verified) ----------------
    f32x4 acc[2];
    acc[0] = (f32x4){0.f, 0.f, 0.f, 0.f};
    acc[1] = (f32x4){0.f, 0.f, 0.f, 0.f};
    const int M = 8;
    int ci = 0;
    for (int m = 0; m < M; ++m) {
        if (m + 1 < M) {
            if (wv < 4) asm volatile("s_waitcnt vmcnt(3)" ::: "memory");
            else        asm volatile("s_waitcnt vmcnt(2)" ::: "memory");
        } else {
            asm volatile("s_waitcnt vmcnt(0)" ::: "memory");
        }
        __builtin_amdgcn_s_barrier();
        if (m + 2 < M) {
            int bi = ci + 2; if (bi >= 3) bi -= 3;
            issue(m + 2, bi);
        }
        const char* bA = smem + ci * 20480;
        const char* bW = bA + 4096;
#pragma unroll
        for (int khi = 0; khi < 2; ++khi) {
            bf16x8 bfr[2];
#pragma unroll
            for (int ni = 0; ni < 2; ++ni) {
                const int wrow = g * 32 + ni * 16 + l15;
                const int j = (khi * 4 + q) ^ (wrow & 7);
                bfr[ni] = *(const bf16x8*)(bW + wrow * 128 + j * 16);
            }
            const int row = mh * 16 + l15;
            const int j = (khi * 4 + q) ^ (row & 7);
            const bf16x8 av = *(const bf16x8*)(bA + row * 128 + j * 16);
            acc[0] = MFMA_BF16(av, bfr[0], acc[0], 0, 0, 0);
            acc[1] = MFMA_BF16(av, bfr[1], acc[1], 0, 0, 0);
        }
        ++ci; if (ci == 3) ci = 0;
    }

    __syncthreads();
    // eg[g][b_local][u_local], stride 33 ; C/D: row=q*4+r, col=l15 [m89]
#pragma unroll
    for (int ni = 0; ni < 2; ++ni)
#pragma unroll
        for (int r = 0; r < 4; ++r)
            eg[(g * 32 + mh * 16 + q * 4 + r) * 33 + ni * 16 + l15] = acc[ni][r];
    __syncthreads();

    // one-way wait: wave 0's 64 lanes poll the grp's 64 packed slots
    // (tag>=t => value valid; memset tag 0 handles t=0's x=0)
    if (wv == 0) {
        const unsigned tu = (unsigned)t;
        u64 v;
        for (;;) {
            v = __hip_atomic_load(&xq[b0 * NCD + lane],
                                  __ATOMIC_RELAXED, __HIP_MEMORY_SCOPE_AGENT);
            if ((unsigned)(v >> 32) >= tu) break;
            __builtin_amdgcn_s_sleep(1);
        }
        union { unsigned u; float f; } cv; cv.u = (unsigned)v;
        xsh[lane] = cv.f;
    }
    __syncthreads();

    // fused pointwise cell update: thread -> unit u, 2 batch rows
    const int u  = tid & 31;
    const int bq = tid >> 5;            // 0..15
    const int ug = u0 + u;
    float bs[4], wx0[4], wx1[4];
#pragma unroll
    for (int g4 = 0; g4 < 4; ++g4) bs[g4] = bsum[g4 * NH + ug];
#pragma unroll
    for (int g4 = 0; g4 < 4; ++g4) {
        wx0[g4] = Wx[(g4 * NH + ug) * 2 + 0];
        wx1[g4] = Wx[(g4 * NH + ug) * 2 + 1];
    }
#pragma unroll
    for (int jj = 0; jj < 2; ++jj) {
        const int bl = bq * 2 + jj;
        const int b  = b0 + bl;
        float gv[4];
#pragma unroll
        for (int g4 = 0; g4 < 4; ++g4) gv[g4] = eg[(g4 * 32 + bl) * 33 + u] + bs[g4];
        const float x0 = xsh[bl * 2 + 0];
        const float x1 = xsh[bl * 2 + 1];
#pragma unroll
        for (int g4 = 0; g4 < 4; ++g4) gv[g4] += x0 * wx0[g4] + x1 * wx1[g4];
        const float iv = sigf(gv[0]);
        const float fv = sigf(gv[1]);
        const float gg = tanhf(gv[2]);
        const float ov = sigf(gv[3]);
        const size_t idx = (size_t)b * NH + ug;
        const float cn = fv * c[idx] + iv * gg;
        c[idx] = cn;
        hnext[idx] = f2b(ov * tanhf(cn));
    }
}

// ---------------------------------------------------------------------------
// LSTM2: R9-verified kernel, unchanged (npass=2, no x-term).
// ---------------------------------------------------------------------------
__global__ __launch_bounds__(512, 4) void lstm_mfma32(
    const u16* __restrict__ A0, const u16* __restrict__ W0,
    const u16* __restrict__ A1, const u16* __restrict__ W1,
    const float* __restrict__ bsum,
    float* __restrict__ c, u16* __restrict__ hnext,
    const int npass)
{
    __shared__ __align__(16) char smem[61440];
    float* eg = (float*)smem;

    const int tid  = threadIdx.x;
    const int lane = tid & 63;
    const int wv   = tid >> 6;
    const int g    = wv & 3;
    const int mh   = wv >> 2;
    const int l15  = lane & 15;
    const int q    = lane >> 4;
    const int bx   = blockIdx.x;
    const int ut   = (bx & 7) * 2 + ((bx >> 3) & 1);
    const int grp  = bx >> 4;
    const int b0   = grp * 32;
    const int u0   = ut * 32;

    int goffW0, goffW1, goffA = 0;
    {
        const int c0 = (wv * 2) * 64 + lane;
        const int w0r = c0 >> 3;
        goffW0 = ((w0r >> 5) * NH + u0 + (w0r & 31)) * NH + (((c0 & 7) ^ (w0r & 7)) * 8);
        const int c1i = (wv * 2 + 1) * 64 + lane;
        const int w1r = c1i >> 3;
        goffW1 = ((w1r >> 5) * NH + u0 + (w1r & 31)) * NH + (((c1i & 7) ^ (w1r & 7)) * 8);
        if (wv < 4) {
            const int ca = wv * 64 + lane;
            const int ar = ca >> 3;
            goffA = (b0 + ar) * NH + (((ca & 7) ^ (ar & 7)) * 8);
        }
    }

    f32x4 acc[2];
    acc[0] = (f32x4){0.f, 0.f, 0.f, 0.f};
    acc[1] = (f32x4){0.f, 0.f, 0.f, 0.f};

    const int M = npass * 8;

    auto issue = [&](int m, int bi) {
        const u16* __restrict__ Ap = (m < 8) ? A0 : A1;
        const u16* __restrict__ Wp = (m < 8) ? W0 : W1;
        const int k0 = (m & 7) * 64;
        char* base = smem + bi * 20480;
        async_cp16((const void*)(Wp + goffW0 + k0),
                   (void*)(base + 4096 + (wv * 2) * 1024));
        async_cp16((const void*)(Wp + goffW1 + k0),
                   (void*)(base + 4096 + (wv * 2 + 1) * 1024));
        if (wv < 4)
            async_cp16((const void*)(Ap + goffA + k0),
                       (void*)(base + wv * 1024));
    };

    issue(0, 0);
    if (M > 1) issue(1, 1);
    int ci = 0;
    for (int m = 0; m < M; ++m) {
        if (m + 1 < M) {
            if (wv < 4) asm volatile("s_waitcnt vmcnt(3)" ::: "memory");
            else        asm volatile("s_waitcnt vmcnt(2)" ::: "memory");
        } else {
            asm volatile("s_waitcnt vmcnt(0)" ::: "memory");
        }
        __builtin_amdgcn_s_barrier();
        if (m + 2 < M) {
            int bi = ci + 2; if (bi >= 3) bi -= 3;
            issue(m + 2, bi);
        }
        const char* bA = smem + ci * 20480;
        const char* bW = bA + 4096;
#pragma unroll
        for (int khi = 0; khi < 2; ++khi) {
            bf16x8 bfr[2];
#pragma unroll
            for (int ni = 0; ni < 2; ++ni) {
                const int wrow = g * 32 + ni * 16 + l15;
                const int j = (khi * 4 + q) ^ (wrow & 7);
                bfr[ni] = *(const bf16x8*)(bW + wrow * 128 + j * 16);
            }
            const int row = mh * 16 + l15;
            const int j = (khi * 4 + q) ^ (row & 7);
            const bf16x8 av = *(const bf16x8*)(bA + row * 128 + j * 16);
            acc[0] = MFMA_BF16(av, bfr[0], acc[0], 0, 0, 0);
            acc[1] = MFMA_BF16(av, bfr[1], acc[1], 0, 0, 0);
        }
        ++ci; if (ci == 3) ci = 0;
    }

    __syncthreads();
#pragma unroll
    for (int ni = 0; ni < 2; ++ni)
#pragma unroll
        for (int r = 0; r < 4; ++r)
            eg[(g * 32 + mh * 16 + q * 4 + r) * 33 + ni * 16 + l15] = acc[ni][r];
    __syncthreads();

    const int u  = tid & 31;
    const int bq = tid >> 5;
    const int ug = u0 + u;
    float bs[4];
#pragma unroll
    for (int g4 = 0; g4 < 4; ++g4) bs[g4] = bsum[g4 * NH + ug];
#pragma unroll
    for (int jj = 0; jj < 2; ++jj) {
        const int bl = bq * 2 + jj;
        const int b  = b0 + bl;
        float gv[4];
#pragma unroll
        for (int g4 = 0; g4 < 4; ++g4) gv[g4] = eg[(g4 * 32 + bl) * 33 + u] + bs[g4];
        const float iv = sigf(gv[0]);
        const float fv = sigf(gv[1]);
        const float gg = tanhf(gv[2]);
        const float ov = sigf(gv[3]);
        const size_t idx = (size_t)b * NH + ug;
        const float cn = fv * c[idx] + iv * gg;
        c[idx] = cn;
        hnext[idx] = f2b(ov * tanhf(cn));
    }
}

// ---------------------------------------------------------------------------
extern "C" void kernel_launch(void* const* d_in, const int* in_sizes, int n_in,
                              void* d_out, int out_size, void* d_ws, size_t ws_size,
                              hipStream_t stream)
{
    const float* zp   = (const float*)d_in[0];
    const float* zsk  = (const float*)d_in[1];
    const float* zst  = (const float*)d_in[2];
    const float* Wp   = (const float*)d_in[3];
    const float* bp   = (const float*)d_in[4];
    const float* Wih1 = (const float*)d_in[5];
    const float* Whh1 = (const float*)d_in[6];
    const float* bih1 = (const float*)d_in[7];
    const float* bhh1 = (const float*)d_in[8];
    const float* Wih2 = (const float*)d_in[9];
    const float* Whh2 = (const float*)d_in[10];
    const float* bih2 = (const float*)d_in[11];
    const float* bhh2 = (const float*)d_in[12];
    const float* Wo1  = (const float*)d_in[13];
    const float* bo1  = (const float*)d_in[14];
    const float* Wo2  = (const float*)d_in[15];
    const float* bo2  = (const float*)d_in[16];

    const size_t BH = (size_t)NB * NH;          // 524288
    u16*   h1a   = (u16*)d_ws;
    u16*   h1b   = h1a + BH;
    u16*   h2a   = h1b + BH;
    u16*   h2b   = h2a + BH;
    float* c1    = (float*)(h2b + BH);
    float* c2    = c1 + BH;
    float* bs1   = c2 + BH;                     // 2048
    float* bs2   = bs1 + 2048;                  // 2048
    u16*   Wo1T  = (u16*)(bs2 + 2048);          // 131072 u16
    u16*   Whh1b = Wo1T + 131072;               // 1048576 each
    u16*   Wih2b = Whh1b + 1048576;
    u16*   Whh2b = Wih2b + 1048576;
    u64*   xq    = (u64*)(Whh2b + 1048576);     // NB*2 u64 = 16 KB, 8-aligned
    // total ~14.3 MB of d_ws

    convert3<<<(2048 * 512) / 256, 256, 0, stream>>>(Whh1, Wih2, Whh2, Whh1b, Wih2b, Whh2b);
    transpose_wo1<<<(256 * 512) / 256, 256, 0, stream>>>(Wo1, Wo1T);
    bsum_k<<<2048 / 256, 256, 0, stream>>>(bih1, bhh1, bih2, bhh2, bs1, bs2);
    hipMemsetAsync(xq, 0, NB * NCD * sizeof(u64), stream);   // tag 0, x = 0
    init_kernel<<<NB / 4, 256, 0, stream>>>(zp, zsk, zst, Wp, bp, h1a, c1, h2a, c2);

    u16* h1c = h1a; u16* h1n = h1b;
    u16* h2c = h2a; u16* h2n = h2b;
    float* outp = (float*)d_out;
    for (int t = 0; t < NT; ++t) {
        fused_out_lstm1<<<512, 512, 0, stream>>>(
            (t == 0) ? (const u16*)0 : h2c, h1c, Whh1b, bs1, xq, Wih1,
            Wo1T, bo1, Wo2, bo2, outp, c1, h1n, t, 1);
        lstm_mfma32<<<512, 512, 0, stream>>>(h1n, Wih2b, h2c, Whh2b,
                                             bs2, c2, h2n, 2);
        u16* tmp = h1c; h1c = h1n; h1n = tmp;
        tmp = h2c; h2c = h2n; h2n = tmp;
    }
    // final out for t = NT-1 (h2c holds h2(NT-1) after the last swap)
    fused_out_lstm1<<<512, 512, 0, stream>>>(
        h2c, h1c, Whh1b, bs1, xq, Wih1,
        Wo1T, bo1, Wo2, bo2, outp, c1, h1n, NT, 0);
}

// Round 12
// 7517.850 us; speedup vs baseline: 1.4786x; 1.2507x over previous
//
#include <hip/hip_runtime.h>
#include <math.h>

// Problem constants
#define NB 1024      // batch
#define NH 512       // hidden
#define NT 256       // time steps
#define NCD 2        // per-step output dims

typedef unsigned short u16;
typedef __bf16 bf16x8 __attribute__((ext_vector_type(8)));
typedef float  f32x4  __attribute__((ext_vector_type(4)));

#define MFMA_BF16 __builtin_amdgcn_mfma_f32_16x16x32_bf16

__device__ __forceinline__ float sigf(float x) { return 1.0f / (1.0f + expf(-x)); }
__device__ __forceinline__ float b2f(u16 u) {
    union { unsigned i; float f; } v; v.i = ((unsigned)u) << 16; return v.f;
}
__device__ __forceinline__ u16 f2b(float f) {   // RTNE
    union { float f; unsigned i; } v; v.f = f;
    unsigned r = v.i + 0x7fffu + ((v.i >> 16) & 1u);
    return (u16)(r >> 16);
}

// async 16B global -> LDS (direct-to-shared DMA); lane L lands at base+L*16.
__device__ __forceinline__ void async_cp16(const void* gptr, void* lptr) {
    __builtin_amdgcn_global_load_lds(
        (const __attribute__((address_space(1))) unsigned int*)gptr,
        (__attribute__((address_space(3))) unsigned int*)lptr,
        16, 0, 0);
}

// ---------------------------------------------------------------------------
// weight conversion fp32 -> bf16 (three 2048x512 LSTM weights)
// ---------------------------------------------------------------------------
__global__ __launch_bounds__(256) void convert3(
    const float* __restrict__ a, const float* __restrict__ b,
    const float* __restrict__ c,
    u16* __restrict__ oa, u16* __restrict__ ob, u16* __restrict__ oc)
{
    const int i = blockIdx.x * 256 + threadIdx.x;   // < 2048*512
    oa[i] = f2b(a[i]); ob[i] = f2b(b[i]); oc[i] = f2b(c[i]);
}

// Wo1 (256x512) fp32 -> bf16, SAME row-major [n][k] layout (B-operand rows)
__global__ __launch_bounds__(256) void convw1(
    const float* __restrict__ a, u16* __restrict__ o)
{
    const int i = blockIdx.x * 256 + threadIdx.x;   // < 256*512
    o[i] = f2b(a[i]);
}

__global__ __launch_bounds__(256) void bsum_k(
    const float* __restrict__ bi1, const float* __restrict__ bh1,
    const float* __restrict__ bi2, const float* __restrict__ bh2,
    float* __restrict__ o1, float* __restrict__ o2)
{
    const int i = blockIdx.x * 256 + threadIdx.x;   // < 2048
    o1[i] = bi1[i] + bh1[i];
    o2[i] = bi2[i] + bh2[i];
}

// ---------------------------------------------------------------------------
// init: [h0 | c0] = z @ W_proj^T + b_proj ; h0 (bf16) -> h1,h2 ; c0 (f32)
// ---------------------------------------------------------------------------
__global__ __launch_bounds__(256) void init_kernel(
    const float* __restrict__ zp, const float* __restrict__ zs,
    const float* __restrict__ zst, const float* __restrict__ Wp,
    const float* __restrict__ bp,
    u16* __restrict__ h1, float* __restrict__ c1,
    u16* __restrict__ h2, float* __restrict__ c2)
{
    __shared__ float z[4][256];
    const int tid = threadIdx.x;
    const int b0  = blockIdx.x * 4;
    for (int i = tid; i < 4 * 256; i += 256) {
        const int bb = i >> 8, k = i & 255;
        float v;
        if (k < 64)       v = zp [(b0 + bb) * 64  + k];
        else if (k < 128) v = zs [(b0 + bb) * 64  + (k - 64)];
        else              v = zst[(b0 + bb) * 128 + (k - 128)];
        z[bb][k] = v;
    }
    __syncthreads();
    for (int rt = 0; rt < 4; ++rt) {
        const int r = rt * 256 + tid;          // 0..1023
        const float bias = bp[r];
        float a0 = bias, a1 = bias, a2 = bias, a3 = bias;
        for (int k = 0; k < 256; ++k) {
            const float w = Wp[r * 256 + k];
            a0 += z[0][k] * w; a1 += z[1][k] * w;
            a2 += z[2][k] * w; a3 += z[3][k] * w;
        }
        const float acc[4] = {a0, a1, a2, a3};
        for (int bb = 0; bb < 4; ++bb) {
            const int b = b0 + bb;
            if (r < NH) {
                h1[b * NH + r] = f2b(acc[bb]);
                h2[b * NH + r] = f2b(acc[bb]);
            } else {
                c1[b * NH + r - NH] = acc[bb];
                c2[b * NH + r - NH] = acc[bb];
            }
        }
    }
}

// ---------------------------------------------------------------------------
// FUSED: out(t-1) + lstm1(t), ZERO inter-block communication.
// Each block computes y(t-1) for its OWN 32 batch rows (16x redundant across
// ut tiles -- bandwidth-equal to the standalone out kernel, MFMA flops free).
// h2(t-1) is complete at the dispatch boundary -> no flags/atomics/fences.
// phaseA: MFMA GEMM M=32,N=256,K=512 (Wo1 bf16 row-major as B), 8 macros,
//   single-buffered (Bo 32KB @0 | A 4KB @32768 | red 2KB @36864); per-wave
//   N-slice n=wv*32..+31; relu+Wo2 reduce via shfl_xor(l15) + LDS red;
//   y kept in REGISTERS (r_x[4]) through phaseB; ut==0 blocks write d_out.
// phaseB: lstm1 K-loop, R9-verified 3-buffer depth-2 vmcnt pipeline.
// ---------------------------------------------------------------------------
__global__ __launch_bounds__(512, 4) void fused_out_lstm1(
    const u16* __restrict__ h2prev,     // null at t=0 -> skip phaseA (x=0)
    const u16* __restrict__ A0,         // h1c
    const u16* __restrict__ W0,         // Whh1 bf16
    const float* __restrict__ bsum,     // bs1
    const float* __restrict__ Wx,       // Wih1 fp32
    const u16* __restrict__ W1b,        // Wo1 bf16 [256][512]
    const float* __restrict__ bo1, const float* __restrict__ Wo2,
    const float* __restrict__ bo2, float* __restrict__ outp,
    float* __restrict__ c, u16* __restrict__ hnext,
    const int t, const int do_lstm)
{
    __shared__ __align__(16) char smem[61440];   // 3 x (As 4KB | Ws 16KB)
    float* eg  = (float*)smem;                   // lstm epilogue alias
    float* red = (float*)(smem + 36864);         // phaseA: [32 m][8 wv][2 cc]

    const int tid  = threadIdx.x;
    const int lane = tid & 63;
    const int wv   = tid >> 6;          // 0..7
    const int g    = wv & 3;            // gate (phaseB)
    const int mh   = wv >> 2;           // batch half (phaseB)
    const int l15  = lane & 15;
    const int q    = lane >> 4;         // 0..3
    const int bx   = blockIdx.x;
    const int ut   = (bx & 7) * 2 + ((bx >> 3) & 1);  // 0..15
    const int grp  = bx >> 4;                          // 0..31
    const int b0   = grp * 32;
    const int u0   = ut * 32;

    // staging descriptors. lstm W: 2 chunks/wave; A: waves 0..3 (32 rows);
    // phaseA Bo (Wo1): 4 chunks/wave (256 rows x 8 kc = 2048 chunks).
    int goffW0, goffW1, goffA = 0, goffO[4];
    {
        const int c0 = (wv * 2) * 64 + lane;        // 0..1023
        const int w0r = c0 >> 3;                    // g*32+uu
        goffW0 = ((w0r >> 5) * NH + u0 + (w0r & 31)) * NH + (((c0 & 7) ^ (w0r & 7)) * 8);
        const int c1i = (wv * 2 + 1) * 64 + lane;
        const int w1r = c1i >> 3;
        goffW1 = ((w1r >> 5) * NH + u0 + (w1r & 31)) * NH + (((c1i & 7) ^ (w1r & 7)) * 8);
        if (wv < 4) {
            const int ca = wv * 64 + lane;          // 0..255
            const int ar = ca >> 3;                 // batch row 0..31
            goffA = (b0 + ar) * NH + (((ca & 7) ^ (ar & 7)) * 8);
        }
#pragma unroll
        for (int i = 0; i < 4; ++i) {
            const int cidx = (wv * 4 + i) * 64 + lane;   // 0..2047
            const int row  = cidx >> 3;                  // n 0..255
            const int kc   = (cidx & 7) ^ (row & 7);
            goffO[i] = row * NH + kc * 8;
        }
    }

    float r_x[4] = {0.f, 0.f, 0.f, 0.f};   // [jj*2+cc], y for rows bq*2+jj

    // ---------------- phase A: out(t-1) for this block's 32 rows -----------
    if (h2prev) {
        f32x4 acc_o[2][2];
#pragma unroll
        for (int mi = 0; mi < 2; ++mi)
#pragma unroll
            for (int ni = 0; ni < 2; ++ni)
                acc_o[mi][ni] = (f32x4){0.f, 0.f, 0.f, 0.f};

        for (int kk = 0; kk < 8; ++kk) {
            __syncthreads();                     // prev macro's readers done
            const int k0 = kk * 64;
#pragma unroll
            for (int i = 0; i < 4; ++i)
                async_cp16((const void*)(W1b + goffO[i] + k0),
                           (void*)(smem + ((wv * 4 + i) << 10)));
            if (wv < 4)
                async_cp16((const void*)(h2prev + goffA + k0),
                           (void*)(smem + 32768 + (wv << 10)));
            asm volatile("s_waitcnt vmcnt(0)" ::: "memory");
            __builtin_amdgcn_s_barrier();
#pragma unroll
            for (int kh = 0; kh < 2; ++kh) {
                bf16x8 bfr[2], av[2];
#pragma unroll
                for (int ni = 0; ni < 2; ++ni) {
                    const int wrow = wv * 32 + ni * 16 + l15;   // n
                    const int j = (kh * 4 + q) ^ (wrow & 7);
                    bfr[ni] = *(const bf16x8*)(smem + wrow * 128 + j * 16);
                }
#pragma unroll
                for (int mi = 0; mi < 2; ++mi) {
                    const int row = mi * 16 + l15;              // m
                    const int j = (kh * 4 + q) ^ (row & 7);
                    av[mi] = *(const bf16x8*)(smem + 32768 + row * 128 + j * 16);
                }
#pragma unroll
                for (int mi = 0; mi < 2; ++mi)
#pragma unroll
                    for (int ni = 0; ni < 2; ++ni)
                        acc_o[mi][ni] = MFMA_BF16(av[mi], bfr[ni], acc_o[mi][ni], 0, 0, 0);
            }
        }
        // epilogue: relu(pre1+bo1) * Wo2, reduce over n
        float bo1n[2], w20[2], w21[2];
#pragma unroll
        for (int ni = 0; ni < 2; ++ni) {
            const int n = wv * 32 + ni * 16 + l15;
            bo1n[ni] = bo1[n]; w20[ni] = Wo2[n]; w21[ni] = Wo2[256 + n];
        }
        float pa[2][4], pb[2][4];
#pragma unroll
        for (int mi = 0; mi < 2; ++mi)
#pragma unroll
            for (int r = 0; r < 4; ++r) {
                const float s0 = fmaxf(acc_o[mi][0][r] + bo1n[0], 0.f);
                const float s1 = fmaxf(acc_o[mi][1][r] + bo1n[1], 0.f);
                pa[mi][r] = s0 * w20[0] + s1 * w20[1];
                pb[mi][r] = s0 * w21[0] + s1 * w21[1];
            }
#pragma unroll
        for (int off = 1; off < 16; off <<= 1)
#pragma unroll
            for (int mi = 0; mi < 2; ++mi)
#pragma unroll
                for (int r = 0; r < 4; ++r) {
                    pa[mi][r] += __shfl_xor(pa[mi][r], off, 64);
                    pb[mi][r] += __shfl_xor(pb[mi][r], off, 64);
                }
        if (l15 == 0) {
#pragma unroll
            for (int mi = 0; mi < 2; ++mi)
#pragma unroll
                for (int r = 0; r < 4; ++r) {
                    const int m = mi * 16 + q * 4 + r;
                    red[m * 16 + wv * 2 + 0] = pa[mi][r];
                    red[m * 16 + wv * 2 + 1] = pb[mi][r];
                }
        }
        __syncthreads();
        if (ut == 0 && tid < 64) {          // one writer tile per grp
            const int bl = tid >> 1, cc = tid & 1;
            float y = bo2[cc];
#pragma unroll
            for (int w8 = 0; w8 < 8; ++w8) y += red[bl * 16 + w8 * 2 + cc];
            outp[(size_t)(b0 + bl) * (NT * NCD) + (t - 1) * NCD + cc] = y;
        }
        if (do_lstm) {                      // everyone grabs its own rows
            const int bq = tid >> 5;        // 0..15
#pragma unroll
            for (int jj = 0; jj < 2; ++jj)
#pragma unroll
                for (int cc = 0; cc < 2; ++cc) {
                    float y = bo2[cc];
#pragma unroll
                    for (int w8 = 0; w8 < 8; ++w8)
                        y += red[(bq * 2 + jj) * 16 + w8 * 2 + cc];
                    r_x[jj * 2 + cc] = y;
                }
        }
        __syncthreads();                    // red reads done before LDS reuse
    }
    if (!do_lstm) return;                   // final out-only dispatch

    // ---------------- phase B: lstm1 K-loop (R9-verified) ----------------
    auto issue = [&](int m, int bi) {
        const int k0 = (m & 7) * 64;
        char* base = smem + bi * 20480;     // As 4KB | Ws 16KB
        async_cp16((const void*)(W0 + goffW0 + k0),
                   (void*)(base + 4096 + (wv * 2) * 1024));
        async_cp16((const void*)(W0 + goffW1 + k0),
                   (void*)(base + 4096 + (wv * 2 + 1) * 1024));
        if (wv < 4)
            async_cp16((const void*)(A0 + goffA + k0),
                       (void*)(base + wv * 1024));
    };

    f32x4 acc[2];
    acc[0] = (f32x4){0.f, 0.f, 0.f, 0.f};
    acc[1] = (f32x4){0.f, 0.f, 0.f, 0.f};
    const int M = 8;
    issue(0, 0); issue(1, 1);
    int ci = 0;
    for (int m = 0; m < M; ++m) {
        if (m + 1 < M) {
            if (wv < 4) asm volatile("s_waitcnt vmcnt(3)" ::: "memory");
            else        asm volatile("s_waitcnt vmcnt(2)" ::: "memory");
        } else {
            asm volatile("s_waitcnt vmcnt(0)" ::: "memory");
        }
        __builtin_amdgcn_s_barrier();
        if (m + 2 < M) {
            int bi = ci + 2; if (bi >= 3) bi -= 3;
            issue(m + 2, bi);
        }
        const char* bA = smem + ci * 20480;
        const char* bW = bA + 4096;
#pragma unroll
        for (int khi = 0; khi < 2; ++khi) {
            bf16x8 bfr[2];
#pragma unroll
            for (int ni = 0; ni < 2; ++ni) {
                const int wrow = g * 32 + ni * 16 + l15;
                const int j = (khi * 4 + q) ^ (wrow & 7);
                bfr[ni] = *(const bf16x8*)(bW + wrow * 128 + j * 16);
            }
            const int row = mh * 16 + l15;
            const int j = (khi * 4 + q) ^ (row & 7);
            const bf16x8 av = *(const bf16x8*)(bA + row * 128 + j * 16);
            acc[0] = MFMA_BF16(av, bfr[0], acc[0], 0, 0, 0);
            acc[1] = MFMA_BF16(av, bfr[1], acc[1], 0, 0, 0);
        }
        ++ci; if (ci == 3) ci = 0;
    }

    __syncthreads();
    // eg[g][b_local][u_local], stride 33 ; C/D: row=q*4+r, col=l15 [m89]
#pragma unroll
    for (int ni = 0; ni < 2; ++ni)
#pragma unroll
        for (int r = 0; r < 4; ++r)
            eg[(g * 32 + mh * 16 + q * 4 + r) * 33 + ni * 16 + l15] = acc[ni][r];
    __syncthreads();

    // fused pointwise cell update: thread -> unit u, 2 batch rows; x from r_x
    const int u  = tid & 31;
    const int bq = tid >> 5;            // 0..15
    const int ug = u0 + u;
    float bs[4], wx0[4], wx1[4];
#pragma unroll
    for (int g4 = 0; g4 < 4; ++g4) bs[g4] = bsum[g4 * NH + ug];
#pragma unroll
    for (int g4 = 0; g4 < 4; ++g4) {
        wx0[g4] = Wx[(g4 * NH + ug) * 2 + 0];
        wx1[g4] = Wx[(g4 * NH + ug) * 2 + 1];
    }
#pragma unroll
    for (int jj = 0; jj < 2; ++jj) {
        const int bl = bq * 2 + jj;
        const int b  = b0 + bl;
        float gv[4];
#pragma unroll
        for (int g4 = 0; g4 < 4; ++g4) gv[g4] = eg[(g4 * 32 + bl) * 33 + u] + bs[g4];
        const float x0 = r_x[jj * 2 + 0];
        const float x1 = r_x[jj * 2 + 1];
#pragma unroll
        for (int g4 = 0; g4 < 4; ++g4) gv[g4] += x0 * wx0[g4] + x1 * wx1[g4];
        const float iv = sigf(gv[0]);
        const float fv = sigf(gv[1]);
        const float gg = tanhf(gv[2]);
        const float ov = sigf(gv[3]);
        const size_t idx = (size_t)b * NH + ug;
        const float cn = fv * c[idx] + iv * gg;
        c[idx] = cn;
        hnext[idx] = f2b(ov * tanhf(cn));
    }
}

// ---------------------------------------------------------------------------
// LSTM2: R9-verified kernel, unchanged (npass=2, no x-term).
// ---------------------------------------------------------------------------
__global__ __launch_bounds__(512, 4) void lstm_mfma32(
    const u16* __restrict__ A0, const u16* __restrict__ W0,
    const u16* __restrict__ A1, const u16* __restrict__ W1,
    const float* __restrict__ bsum,
    float* __restrict__ c, u16* __restrict__ hnext,
    const int npass)
{
    __shared__ __align__(16) char smem[61440];
    float* eg = (float*)smem;

    const int tid  = threadIdx.x;
    const int lane = tid & 63;
    const int wv   = tid >> 6;
    const int g    = wv & 3;
    const int mh   = wv >> 2;
    const int l15  = lane & 15;
    const int q    = lane >> 4;
    const int bx   = blockIdx.x;
    const int ut   = (bx & 7) * 2 + ((bx >> 3) & 1);
    const int grp  = bx >> 4;
    const int b0   = grp * 32;
    const int u0   = ut * 32;

    int goffW0, goffW1, goffA = 0;
    {
        const int c0 = (wv * 2) * 64 + lane;
        const int w0r = c0 >> 3;
        goffW0 = ((w0r >> 5) * NH + u0 + (w0r & 31)) * NH + (((c0 & 7) ^ (w0r & 7)) * 8);
        const int c1i = (wv * 2 + 1) * 64 + lane;
        const int w1r = c1i >> 3;
        goffW1 = ((w1r >> 5) * NH + u0 + (w1r & 31)) * NH + (((c1i & 7) ^ (w1r & 7)) * 8);
        if (wv < 4) {
            const int ca = wv * 64 + lane;
            const int ar = ca >> 3;
            goffA = (b0 + ar) * NH + (((ca & 7) ^ (ar & 7)) * 8);
        }
    }

    f32x4 acc[2];
    acc[0] = (f32x4){0.f, 0.f, 0.f, 0.f};
    acc[1] = (f32x4){0.f, 0.f, 0.f, 0.f};

    const int M = npass * 8;

    auto issue = [&](int m, int bi) {
        const u16* __restrict__ Ap = (m < 8) ? A0 : A1;
        const u16* __restrict__ Wp = (m < 8) ? W0 : W1;
        const int k0 = (m & 7) * 64;
        char* base = smem + bi * 20480;
        async_cp16((const void*)(Wp + goffW0 + k0),
                   (void*)(base + 4096 + (wv * 2) * 1024));
        async_cp16((const void*)(Wp + goffW1 + k0),
                   (void*)(base + 4096 + (wv * 2 + 1) * 1024));
        if (wv < 4)
            async_cp16((const void*)(Ap + goffA + k0),
                       (void*)(base + wv * 1024));
    };

    issue(0, 0);
    if (M > 1) issue(1, 1);
    int ci = 0;
    for (int m = 0; m < M; ++m) {
        if (m + 1 < M) {
            if (wv < 4) asm volatile("s_waitcnt vmcnt(3)" ::: "memory");
            else        asm volatile("s_waitcnt vmcnt(2)" ::: "memory");
        } else {
            asm volatile("s_waitcnt vmcnt(0)" ::: "memory");
        }
        __builtin_amdgcn_s_barrier();
        if (m + 2 < M) {
            int bi = ci + 2; if (bi >= 3) bi -= 3;
            issue(m + 2, bi);
        }
        const char* bA = smem + ci * 20480;
        const char* bW = bA + 4096;
#pragma unroll
        for (int khi = 0; khi < 2; ++khi) {
            bf16x8 bfr[2];
#pragma unroll
            for (int ni = 0; ni < 2; ++ni) {
                const int wrow = g * 32 + ni * 16 + l15;
                const int j = (khi * 4 + q) ^ (wrow & 7);
                bfr[ni] = *(const bf16x8*)(bW + wrow * 128 + j * 16);
            }
            const int row = mh * 16 + l15;
            const int j = (khi * 4 + q) ^ (row & 7);
            const bf16x8 av = *(const bf16x8*)(bA + row * 128 + j * 16);
            acc[0] = MFMA_BF16(av, bfr[0], acc[0], 0, 0, 0);
            acc[1] = MFMA_BF16(av, bfr[1], acc[1], 0, 0, 0);
        }
        ++ci; if (ci == 3) ci = 0;
    }

    __syncthreads();
#pragma unroll
    for (int ni = 0; ni < 2; ++ni)
#pragma unroll
        for (int r = 0; r < 4; ++r)
            eg[(g * 32 + mh * 16 + q * 4 + r) * 33 + ni * 16 + l15] = acc[ni][r];
    __syncthreads();

    const int u  = tid & 31;
    const int bq = tid >> 5;
    const int ug = u0 + u;
    float bs[4];
#pragma unroll
    for (int g4 = 0; g4 < 4; ++g4) bs[g4] = bsum[g4 * NH + ug];
#pragma unroll
    for (int jj = 0; jj < 2; ++jj) {
        const int bl = bq * 2 + jj;
        const int b  = b0 + bl;
        float gv[4];
#pragma unroll
        for (int g4 = 0; g4 < 4; ++g4) gv[g4] = eg[(g4 * 32 + bl) * 33 + u] + bs[g4];
        const float iv = sigf(gv[0]);
        const float fv = sigf(gv[1]);
        const float gg = tanhf(gv[2]);
        const float ov = sigf(gv[3]);
        const size_t idx = (size_t)b * NH + ug;
        const float cn = fv * c[idx] + iv * gg;
        c[idx] = cn;
        hnext[idx] = f2b(ov * tanhf(cn));
    }
}

// ---------------------------------------------------------------------------
extern "C" void kernel_launch(void* const* d_in, const int* in_sizes, int n_in,
                              void* d_out, int out_size, void* d_ws, size_t ws_size,
                              hipStream_t stream)
{
    const float* zp   = (const float*)d_in[0];
    const float* zsk  = (const float*)d_in[1];
    const float* zst  = (const float*)d_in[2];
    const float* Wp   = (const float*)d_in[3];
    const float* bp   = (const float*)d_in[4];
    const float* Wih1 = (const float*)d_in[5];
    const float* Whh1 = (const float*)d_in[6];
    const float* bih1 = (const float*)d_in[7];
    const float* bhh1 = (const float*)d_in[8];
    const float* Wih2 = (const float*)d_in[9];
    const float* Whh2 = (const float*)d_in[10];
    const float* bih2 = (const float*)d_in[11];
    const float* bhh2 = (const float*)d_in[12];
    const float* Wo1  = (const float*)d_in[13];
    const float* bo1  = (const float*)d_in[14];
    const float* Wo2  = (const float*)d_in[15];
    const float* bo2  = (const float*)d_in[16];

    const size_t BH = (size_t)NB * NH;          // 524288
    u16*   h1a   = (u16*)d_ws;
    u16*   h1b   = h1a + BH;
    u16*   h2a   = h1b + BH;
    u16*   h2b   = h2a + BH;
    float* c1    = (float*)(h2b + BH);
    float* c2    = c1 + BH;
    float* bs1   = c2 + BH;                     // 2048
    float* bs2   = bs1 + 2048;                  // 2048
    u16*   Wo1b  = (u16*)(bs2 + 2048);          // 131072 u16 (row-major bf16)
    u16*   Whh1b = Wo1b + 131072;               // 1048576 each
    u16*   Wih2b = Whh1b + 1048576;
    u16*   Whh2b = Wih2b + 1048576;
    // total ~14.3 MB of d_ws

    convert3<<<(2048 * 512) / 256, 256, 0, stream>>>(Whh1, Wih2, Whh2, Whh1b, Wih2b, Whh2b);
    convw1<<<(256 * 512) / 256, 256, 0, stream>>>(Wo1, Wo1b);
    bsum_k<<<2048 / 256, 256, 0, stream>>>(bih1, bhh1, bih2, bhh2, bs1, bs2);
    init_kernel<<<NB / 4, 256, 0, stream>>>(zp, zsk, zst, Wp, bp, h1a, c1, h2a, c2);

    u16* h1c = h1a; u16* h1n = h1b;
    u16* h2c = h2a; u16* h2n = h2b;
    float* outp = (float*)d_out;
    for (int t = 0; t < NT; ++t) {
        fused_out_lstm1<<<512, 512, 0, stream>>>(
            (t == 0) ? (const u16*)0 : h2c, h1c, Whh1b, bs1, Wih1,
            Wo1b, bo1, Wo2, bo2, outp, c1, h1n, t, 1);
        lstm_mfma32<<<512, 512, 0, stream>>>(h1n, Wih2b, h2c, Whh2b,
                                             bs2, c2, h2n, 2);
        u16* tmp = h1c; h1c = h1n; h1n = tmp;
        tmp = h2c; h2c = h2n; h2n = tmp;
    }
    // final out for t = NT-1 (h2c holds h2(NT-1) after the last swap)
    fused_out_lstm1<<<512, 512, 0, stream>>>(
        h2c, h1c, Whh1b, bs1, Wih1,
        Wo1b, bo1, Wo2, bo2, outp, c1, h1n, NT, 0);
}